// Round 5
// baseline (169.014 us; speedup 1.0000x reference)
//
#include <hip/hip_runtime.h>
#include <cstdint>
#include <cmath>

#define NROWS 8192
#define KDIM  512            // elements; also bytes/row in fp8

typedef int    i32x4  __attribute__((ext_vector_type(4)));
typedef int    i32x8  __attribute__((ext_vector_type(8)));
typedef float  f32x16 __attribute__((ext_vector_type(16)));
typedef unsigned char u8;

#define AS1(p) ((const __attribute__((address_space(1))) void*)(p))
#define AS3(p) ((__attribute__((address_space(3))) void*)(p))

// --- Kernel 1: row L2-normalize fp32 -> fp8 e4m3 (OCP, HW cvt), one wave/row.
// zi rows [0,8192), zj rows [8192,16384). Also zeroes the 128 accumulator slots.
__global__ __launch_bounds__(256) void nrm_kernel(const float* __restrict__ zi,
                                                  const float* __restrict__ zj,
                                                  u8* __restrict__ out,
                                                  double* __restrict__ acc) {
    if (blockIdx.x == 0 && threadIdx.x < 128) acc[threadIdx.x] = 0.0;
    const int wave = threadIdx.x >> 6;
    const int lane = threadIdx.x & 63;
    const int row  = blockIdx.x * 4 + wave;            // 0..16383
    const float* src = (row < NROWS) ? zi + (size_t)row * KDIM
                                     : zj + (size_t)(row - NROWS) * KDIM;
    float4 a = ((const float4*)src)[lane];
    float4 b = ((const float4*)src)[lane + 64];
    float ss = a.x*a.x + a.y*a.y + a.z*a.z + a.w*a.w
             + b.x*b.x + b.y*b.y + b.z*b.z + b.w*b.w;
    #pragma unroll
    for (int off = 32; off >= 1; off >>= 1) ss += __shfl_xor(ss, off, 64);
    const float inv = 1.0f / fmaxf(sqrtf(ss), 1e-12f);
    int p0 = 0, p1 = 0;
    p0 = __builtin_amdgcn_cvt_pk_fp8_f32(a.x * inv, a.y * inv, p0, false);
    p0 = __builtin_amdgcn_cvt_pk_fp8_f32(a.z * inv, a.w * inv, p0, true);
    p1 = __builtin_amdgcn_cvt_pk_fp8_f32(b.x * inv, b.y * inv, p1, false);
    p1 = __builtin_amdgcn_cvt_pk_fp8_f32(b.z * inv, b.w * inv, p1, true);
    int* dst = (int*)(out + (size_t)row * KDIM);
    dst[lane]      = p0;
    dst[lane + 64] = p1;
}

// --- Kernel 2: fused MX-fp8 A*B^T -> exp(10*dot) -> global sum.
// R16: GEOMETRY change (schedule class exhausted: R11/R14/R15 all 83+-2 us,
// MfmaUtil ~25%). Block 256x256, 8 waves (512 thr), wave tile 128x64 (2Mx4N)
// — the verified inner loop (frag layout, swizzle, MFMA) is UNCHANGED.
// Why: per-step economics, not latency, pin the old shape. 256x128 staged
// 24 KB per 32 MFMAs (1.5 b128-reads/MFMA, LDS port ~75% of wall); 256x256
// stages 32 KB per 64 MFMAs, stage-loads/thread 6->4, barriers amortized 2x.
// Registers (~100 VGPR + 128 AGPR acc => ~8 waves/CU) cap residency at 1
// block of 8 waves regardless of LDS, so triple-buffer LDS (96 KB) is free:
// R15-proven rotation (read buf t%3, stage t+2 into (t+2)%3 after the top
// barrier; counted vmcnt(4) keeps tile t+1 in flight across the barrier,
// never draining to 0 until the last step). Reads split in two phase
// clusters (8 then 4) so the first MFMA quad starts after 8 reads, and
// stage-issues are spread between them. setprio only around MFMA clusters.
// LDS XOR-swizzle unchanged (verified R2-R15, absmax 0): region = 32 rows x
// 64 B; chunk (r,b) at p = r*4 + (b ^ ((r>>1)&3)); staging inverse
// b = (lane&3)^((lane>>3)&3). Triangle logic now square: pos = bx<32,
// skip bx<by, diag bx==by skips rr==cc, bx>by weight 2. Relaxed atomicAdd +
// separate finalize (R12/R13 lesson: fused finalize's agent-scope acquire =
// per-block L2 invalidate = 2x regression; never re-fuse).
__global__ __launch_bounds__(512, 1) void gemm_exp_reduce(const u8* __restrict__ A,
                                                          const u8* __restrict__ B,
                                                          double* __restrict__ acc) {
    const int bx = blockIdx.x, by = blockIdx.y;
    const bool pos = (bx < 32);
    if (pos && bx < by) return;      // strict lower-tri pos block: mirror elsewhere

    __shared__ u8 lA0[256 * 64];     // 16 KB each (8 regions of 32r x 64B)
    __shared__ u8 lA1[256 * 64];
    __shared__ u8 lA2[256 * 64];
    __shared__ u8 lB0[256 * 64];     // B tile now 256 rows as well
    __shared__ u8 lB1[256 * 64];
    __shared__ u8 lB2[256 * 64];
    __shared__ float red[8];

    const int tid  = threadIdx.x;
    const int lane = tid & 63;
    const int wave = tid >> 6;                 // 0..7
    const int m0   = by * 256;
    const int n0   = bx * 256;
    const int wm   = (wave >> 2) * 128;        // 2 M-groups
    const int wn   = (wave & 3) * 64;          // 4 N-groups

    f32x16 accf[4][2];
    #pragma unroll
    for (int i = 0; i < 4; ++i)
        #pragma unroll
        for (int j = 0; j < 2; ++j)
            #pragma unroll
            for (int r = 0; r < 16; ++r)
                accf[i][j][r] = 0.f;

    // staging: each wave stages its 32-row region (= region index `wave`) of
    // BOTH A and B: 2 chunks of 16 rows x 1024 B each. 4 loads/thread/step.
    // lane: row = wave*32 + c*16 + (lane>>2), 16B-col bsw = (lane&3)^((lane>>3)&3).
    const int bsw = (lane & 3) ^ ((lane >> 3) & 3);
    const u8* gA0 = A + (size_t)(m0 + wave * 32 + (lane >> 2)) * KDIM + bsw * 16;
    const u8* gB0 = B + (size_t)(n0 + wave * 32 + (lane >> 2)) * KDIM + bsw * 16;
    const int ldsO = wave * 2048 + lane * 16;

    auto stageA = [&](int t, u8 (&dA)[256 * 64]) {
        const size_t kb = (size_t)t * 64;
        #pragma unroll
        for (int c = 0; c < 2; ++c)
            __builtin_amdgcn_global_load_lds(AS1(gA0 + kb + (size_t)c * 16 * KDIM),
                                             AS3(&dA[ldsO + c * 1024]), 16, 0, 0);
    };
    auto stageB = [&](int t, u8 (&dB)[256 * 64]) {
        const size_t kb = (size_t)t * 64;
        #pragma unroll
        for (int c = 0; c < 2; ++c)
            __builtin_amdgcn_global_load_lds(AS1(gB0 + kb + (size_t)c * 16 * KDIM),
                                             AS3(&dB[ldsO + c * 1024]), 16, 0, 0);
    };

    // fragment read (verified layout): lane row r=lane&31, k-half q=lane>>5;
    // swizzled position p = r*4 + ((2q) ^ ((r>>1)&3)); partner chunk at ^16.
    const int r_  = lane & 31;
    const int q_  = lane >> 5;
    const int p16 = (r_ * 4 + ((2 * q_) ^ ((r_ >> 1) & 3))) * 16;
    const int aT0 = (wave >> 2) * 4;   // A regions aT0..aT0+3 (128 rows)
    const int bT0 = (wave & 3) * 2;    // B regions bT0..bT0+1 (64 rows)

    auto rdA = [&](const u8 (&sA)[256 * 64], int mi, i32x8& v) {
        const int off = (aT0 + mi) * 2048 + p16;
        *(i32x4*)&v       = *(const i32x4*)&sA[off];
        *((i32x4*)&v + 1) = *(const i32x4*)&sA[off ^ 16];
    };
    auto rdB = [&](const u8 (&sB)[256 * 64], int ni, i32x8& v) {
        const int off = (bT0 + ni) * 2048 + p16;
        *(i32x4*)&v       = *(const i32x4*)&sB[off];
        *((i32x4*)&v + 1) = *(const i32x4*)&sB[off ^ 16];
    };

    auto mm = [&](const i32x8& a, const i32x8 (&bfr)[2], f32x16 (&ac)[2]) {
        #pragma unroll
        for (int ni = 0; ni < 2; ++ni)
            ac[ni] = __builtin_amdgcn_mfma_scale_f32_32x32x64_f8f6f4(
                a, bfr[ni], ac[ni],
                0, 0,                 // cbsz=fp8(e4m3), blgp=fp8(e4m3)
                0, 0x7f7f7f7f,        // scale_a: every byte = 2^0
                0, 0x7f7f7f7f);       // scale_b
    };

    stageA(0, lA0); stageB(0, lB0);    // 4 loads in flight
    stageA(1, lA1); stageB(1, lB1);    // 8 in flight

    // Per step: vmcnt(4) = tile t landed, tile t+1 stays in flight ACROSS the
    // barrier. Phase 0: read af0,af1,bf0,bf1 (8 b128) + stage A(t+2) -> 4 MFMA;
    // phase 1: read af2,af3 (4 b128) + stage B(t+2) -> 4 MFMA.
#define GSTEP(RA, RB, TS, SA, SB, VM)                                  \
    {                                                                  \
        asm volatile("s_waitcnt vmcnt(" #VM ")" ::: "memory");         \
        __builtin_amdgcn_s_barrier();                                  \
        i32x8 af0, af1, af2, af3; i32x8 bfr[2];                        \
        rdA(RA, 0, af0); rdA(RA, 1, af1);                              \
        rdB(RB, 0, bfr[0]); rdB(RB, 1, bfr[1]);                        \
        if ((TS) >= 0) stageA((TS), SA);                               \
        asm volatile("s_waitcnt lgkmcnt(0)" ::: "memory");             \
        __builtin_amdgcn_sched_barrier(0);                             \
        __builtin_amdgcn_s_setprio(1);                                 \
        mm(af0, bfr, accf[0]); mm(af1, bfr, accf[1]);                  \
        __builtin_amdgcn_s_setprio(0);                                 \
        rdA(RA, 2, af2); rdA(RA, 3, af3);                              \
        if ((TS) >= 0) stageB((TS), SB);                               \
        asm volatile("s_waitcnt lgkmcnt(0)" ::: "memory");             \
        __builtin_amdgcn_sched_barrier(0);                             \
        __builtin_amdgcn_s_setprio(1);                                 \
        mm(af2, bfr, accf[2]); mm(af3, bfr, accf[3]);                  \
        __builtin_amdgcn_s_setprio(0);                                 \
    }

    GSTEP(lA0, lB0,  2, lA2, lB2, 4)   // t=0
    GSTEP(lA1, lB1,  3, lA0, lB0, 4)   // t=1
    GSTEP(lA2, lB2,  4, lA1, lB1, 4)   // t=2
    GSTEP(lA0, lB0,  5, lA2, lB2, 4)   // t=3
    GSTEP(lA1, lB1,  6, lA0, lB0, 4)   // t=4
    GSTEP(lA2, lB2,  7, lA1, lB1, 4)   // t=5
    GSTEP(lA0, lB0, -1, lA1, lB1, 4)   // t=6: tile7 still in flight
    GSTEP(lA1, lB1, -1, lA1, lB1, 0)   // t=7: final drain
#undef GSTEP

    // epilogue: exp(10*d) = exp2(d*10/ln2); diag pos block skips rr==cc
    const float LOG2E10 = 14.4269504088896341f;
    float part = 0.f;
    if (pos && bx == by) {
        #pragma unroll
        for (int mi = 0; mi < 4; ++mi)
            #pragma unroll
            for (int ni = 0; ni < 2; ++ni)
                #pragma unroll
                for (int r = 0; r < 16; ++r) {
                    // C/D 32x32: col=lane&31, row=(r&3)+8*(r>>2)+4*(lane>>5)
                    int rr = m0 + wm + mi * 32 + ((r & 3) + 8 * (r >> 2) + 4 * q_);
                    int cc = n0 + wn + ni * 32 + r_;
                    if (rr != cc) part += exp2f(accf[mi][ni][r] * LOG2E10);
                }
    } else {
        #pragma unroll
        for (int mi = 0; mi < 4; ++mi)
            #pragma unroll
            for (int ni = 0; ni < 2; ++ni)
                #pragma unroll
                for (int r = 0; r < 16; ++r)
                    part += exp2f(accf[mi][ni][r] * LOG2E10);
    }

    #pragma unroll
    for (int off = 32; off >= 1; off >>= 1) part += __shfl_xor(part, off, 64);
    if (lane == 0) red[wave] = part;
    __syncthreads();
    if (tid == 0) {
        double s = 0.0;
        #pragma unroll
        for (int w = 0; w < 8; ++w) s += (double)red[w];
        if (pos && bx > by) s *= 2.0;    // stands in for its skipped mirror
        atomicAdd(&acc[(pos ? 0 : 64) + (((unsigned)bx * 7 + (unsigned)by) & 63)], s);
    }
}

// --- Kernel 3: loss = log1p(neg/pos), pos += exact diagonal 8192*e^10.
// 128 threads, one global load each; LDS reduce then scalar finish.
__global__ __launch_bounds__(128) void finalize(const double* __restrict__ acc,
                                                float* __restrict__ out) {
    __shared__ double sp[128];
    const int t = threadIdx.x;
    sp[t] = acc[t];
    __syncthreads();
    if (t == 0) {
        double p = 0.0, n = 0.0;
        #pragma unroll
        for (int i = 0; i < 64; ++i) { p += sp[i]; n += sp[64 + i]; }
        p += 8192.0 * exp(10.0);
        out[0] = (float)log1p(n / p);
    }
}

extern "C" void kernel_launch(void* const* d_in, const int* in_sizes, int n_in,
                              void* d_out, int out_size, void* d_ws, size_t ws_size,
                              hipStream_t stream) {
    const float* zi = (const float*)d_in[0];
    const float* zj = (const float*)d_in[1];
    u8* nrm = (u8*)d_ws;                                      // [16384][512] fp8 = 8 MB
    double* acc = (double*)((char*)d_ws + (size_t)16384 * 512);

    nrm_kernel<<<4096, 256, 0, stream>>>(zi, zj, nrm, acc);
    dim3 grid(64, 32);   // x: 16384/256 n-tiles, y: 8192/256 m-tiles
    gemm_exp_reduce<<<grid, 512, 0, stream>>>(nrm, nrm, acc);
    finalize<<<1, 128, 0, stream>>>(acc, (float*)d_out);
}